// Round 10
// baseline (922.495 us; speedup 1.0000x reference)
//
#include <hip/hip_runtime.h>
#include <math.h>

#define B_   2
#define S_   2048
#define H_   2048
#define NH_  16
#define T_   (B_*S_)      // 4096 tokens
#define QL   1536
#define KVL  512
#define DN   128
#define DR   64
#define DQK  192          // DN + DR
#define DV   128
#define SCALE_ 0.07216878364870323f   // 1/sqrt(192)
#define EPS_ 1e-6f
#define NQKV 2176                     // fused q_a(1536) + kv_a(640) output cols

typedef unsigned short u16;
typedef __attribute__((ext_vector_type(8))) short bf16x8;  // 8 bf16 = 4 VGPRs
typedef __attribute__((ext_vector_type(4))) float f32x4;   // MFMA C/D frag

__device__ __forceinline__ u16 f2b(float x) {   // fp32 -> bf16 RNE
  union { float f; unsigned u; } v; v.f = x;
  unsigned r = v.u + 0x7FFFu + ((v.u >> 16) & 1u);
  return (u16)(r >> 16);
}
__device__ __forceinline__ float b2f(u16 u) {
  union { unsigned u; float f; } v; v.u = ((unsigned)u) << 16; return v.f;
}

#define GLD16(src, dst) __builtin_amdgcn_global_load_lds(                       \
    (const __attribute__((address_space(1))) unsigned int*)(src),               \
    (__attribute__((address_space(3))) unsigned int*)(dst), 16, 0, 0)

__device__ __forceinline__ void cvt4(const float* in, u16* out, int i) {
  float4 v = ((const float4*)in)[i];
  u16 r[4] = {f2b(v.x), f2b(v.y), f2b(v.z), f2b(v.w)};
  ((uint2*)out)[i] = *(uint2*)r;
}

// ---------------------------------------------------------------------------
// One fused conversion kernel: hidden + all 4 weights (wkv_a padded 576->640).
// ---------------------------------------------------------------------------
__global__ __launch_bounds__(256) void cvt_all(
    const float* __restrict__ hid, const float* __restrict__ wqa,
    const float* __restrict__ wqb, const float* __restrict__ wkva,
    const float* __restrict__ wkvb, const float* __restrict__ wo,
    u16* __restrict__ o_hid, u16* __restrict__ o_wqa, u16* __restrict__ o_wqb,
    u16* __restrict__ o_wkva, u16* __restrict__ o_wkvb, u16* __restrict__ o_wo) {
  int i = blockIdx.x * 256 + threadIdx.x;
  if (i < 2097152) { cvt4(hid, o_hid, i); return; }
  i -= 2097152;
  if (i < 786432) { cvt4(wqa, o_wqa, i); return; }
  i -= 786432;
  if (i < 1179648) { cvt4(wqb, o_wqb, i); return; }
  i -= 1179648;
  if (i < 327680) {                       // wkv_a with zero-pad rows [576,640)
    int row = i >> 9;
    u16 r[4] = {0, 0, 0, 0};
    if (row < 576) {
      float4 v = ((const float4*)wkva)[i];
      r[0] = f2b(v.x); r[1] = f2b(v.y); r[2] = f2b(v.z); r[3] = f2b(v.w);
    }
    ((uint2*)o_wkva)[i] = *(uint2*)r;
    return;
  }
  i -= 327680;
  if (i < 524288) { cvt4(wkvb, o_wkvb, i); return; }
  i -= 524288;
  if (i < 1048576) cvt4(wo, o_wo, i);
}

// ---------------------------------------------------------------------------
// bf16 MFMA GEMM: C = A @ W^T — round-5/6 measured-best BK=32 version.
// ---------------------------------------------------------------------------
template <int OUTMODE>
__global__ __launch_bounds__(256) void gemm_mfma(
    const u16* __restrict__ A, int lda,
    const u16* __restrict__ W, int ldw,
    float* __restrict__ Cf, u16* __restrict__ Cb, int ldc,
    int K, float outscale) {
  __shared__ u16 As[4096];   // 8 KB
  __shared__ u16 Bs[4096];
  const int tid = threadIdx.x;
  const int wave = tid >> 6, lane = tid & 63, quad = lane >> 4, l16 = lane & 15;
  const int wm = (wave >> 1) * 64, wn = (wave & 1) * 64;
  const size_t m0 = (size_t)blockIdx.y * 128, n0 = (size_t)blockIdx.x * 128;

  f32x4 acc[4][4];
#pragma unroll
  for (int i = 0; i < 4; ++i)
#pragma unroll
    for (int j = 0; j < 4; ++j) acc[i][j] = (f32x4){0.f, 0.f, 0.f, 0.f};

  const int g0 = tid, g1 = tid + 256;
  const u16* a0 = A + (m0 + (g0 >> 6) * 16 + (g0 & 15)) * (size_t)lda + ((g0 >> 4) & 3) * 8;
  const u16* a1 = A + (m0 + (g1 >> 6) * 16 + (g1 & 15)) * (size_t)lda + ((g1 >> 4) & 3) * 8;
  const u16* b0 = W + (n0 + (g0 >> 6) * 16 + (g0 & 15)) * (size_t)ldw + ((g0 >> 4) & 3) * 8;
  const u16* b1 = W + (n0 + (g1 >> 6) * 16 + (g1 & 15)) * (size_t)ldw + ((g1 >> 4) & 3) * 8;

  for (int k0 = 0; k0 < K; k0 += 32) {
    __syncthreads();
    GLD16(a0 + k0, &As[g0 * 8]);
    GLD16(a1 + k0, &As[g1 * 8]);
    GLD16(b0 + k0, &Bs[g0 * 8]);
    GLD16(b1 + k0, &Bs[g1 * 8]);
    __syncthreads();

    bf16x8 af[4], bfr[4];
#pragma unroll
    for (int i = 0; i < 4; ++i)
      af[i] = *(const bf16x8*)&As[((wm >> 4) + i) * 512 + quad * 128 + l16 * 8];
#pragma unroll
    for (int j = 0; j < 4; ++j)
      bfr[j] = *(const bf16x8*)&Bs[((wn >> 4) + j) * 512 + quad * 128 + l16 * 8];
#pragma unroll
    for (int i = 0; i < 4; ++i)
#pragma unroll
      for (int j = 0; j < 4; ++j)
        acc[i][j] = __builtin_amdgcn_mfma_f32_16x16x32_bf16(af[i], bfr[j], acc[i][j], 0, 0, 0);
  }

#pragma unroll
  for (int i = 0; i < 4; ++i)
#pragma unroll
    for (int j = 0; j < 4; ++j)
#pragma unroll
      for (int r = 0; r < 4; ++r) {
        size_t m = m0 + wm + i * 16 + quad * 4 + r;
        size_t n = n0 + wn + j * 16 + l16;
        if (OUTMODE == 0) Cf[m * ldc + n] = acc[i][j][r];
        else              Cb[m * ldc + n] = f2b(acc[i][j][r] * outscale);
      }
}

// ---------------------------------------------------------------------------
// RMSNorm: fp32 in (row stride sx), bf16 out (row stride so), D cols.
// ---------------------------------------------------------------------------
__global__ __launch_bounds__(256) void rmsnorm_bf(
    const float* __restrict__ x, const float* __restrict__ w,
    u16* __restrict__ o, int D, int sx, int so) {
  const float* p = x + (size_t)blockIdx.x * sx;
  u16* q = o + (size_t)blockIdx.x * so;
  float ss = 0.f;
  for (int i = threadIdx.x; i < D; i += 256) { float v = p[i]; ss += v * v; }
#pragma unroll
  for (int off = 32; off; off >>= 1) ss += __shfl_down(ss, off);
  __shared__ float red[4];
  __shared__ float s_inv;
  if ((threadIdx.x & 63) == 0) red[threadIdx.x >> 6] = ss;
  __syncthreads();
  if (threadIdx.x == 0) {
    float t = red[0] + red[1] + red[2] + red[3];
    s_inv = 1.0f / sqrtf(t / (float)D + EPS_);
  }
  __syncthreads();
  float inv = s_inv;
  for (int i = threadIdx.x; i < D; i += 256) q[i] = f2b(w[i] * p[i] * inv);
}

// ---------------------------------------------------------------------------
// RoPE cos/sin table: bit-identical expressions, computed once (65536 entries).
// ---------------------------------------------------------------------------
__global__ __launch_bounds__(256) void rope_tab_kernel(float* __restrict__ Tab) {
  int idx = blockIdx.x * 256 + threadIdx.x;   // S_*32 = 65536
  int pair = idx & 31;
  int s = idx >> 5;
  float inv = powf(10000.0f, -(float)(2 * pair) * (1.0f / 64.0f));
  float ang = (float)s * inv;
  ((float2*)Tab)[idx] = make_float2(cosf(ang), sinf(ang));
}

// RoPE in place on bf16 q_pe. Q: [T][NH*192], pe at +128 per head.
__global__ void rope_q_bf(u16* __restrict__ Q, const float* __restrict__ Tab) {
  int idx = blockIdx.x * blockDim.x + threadIdx.x;   // T*NH*32
  int pair = idx & 31;
  int head = (idx >> 5) & (NH_ - 1);
  int row = idx >> 9;
  if (row >= T_) return;
  int s = row & (S_ - 1);
  float2 cs = ((const float2*)Tab)[(s << 5) | pair];
  float c = cs.x, sn = cs.y;
  u16* p = Q + (size_t)row * (NH_ * DQK) + head * DQK + DN + 2 * pair;
  unsigned u = *(unsigned*)p;
  float e = b2f((u16)(u & 0xffff)), o = b2f((u16)(u >> 16));
  float re = e * c - o * sn;
  float im = e * sn + o * c;
  *(unsigned*)p = (unsigned)f2b(re) | ((unsigned)f2b(im) << 16);
}

// k_pe: fp32 qkv_a cols [2048,2112) (row stride 2176), rope -> bf16 KPE [T][64].
__global__ void kpe_bf_kernel(const float* __restrict__ KVa, u16* __restrict__ KPE,
                              const float* __restrict__ Tab) {
  int idx = blockIdx.x * blockDim.x + threadIdx.x;   // T*32
  int pair = idx & 31;
  int row = idx >> 5;
  if (row >= T_) return;
  int s = row & (S_ - 1);
  float2 cs = ((const float2*)Tab)[(s << 5) | pair];
  float c = cs.x, sn = cs.y;
  const float* p = KVa + (size_t)row * NQKV + 2048 + 2 * pair;
  float e = p[0], o = p[1];
  float re = e * c - o * sn;
  float im = e * sn + o * c;
  *(unsigned*)(KPE + (size_t)row * 64 + 2 * pair) =
      (unsigned)f2b(re) | ((unsigned)f2b(im) << 16);
}

// ---------------------------------------------------------------------------
// V transpose: KVbf [T][NH*256] (v at +128 per head) -> Vt [B*NH*128][2048].
// ---------------------------------------------------------------------------
__global__ __launch_bounds__(256) void conv_vt(const u16* __restrict__ KVbf,
                                               u16* __restrict__ Vt) {
  const int h = blockIdx.y, b = blockIdx.z;
  const int s0 = (blockIdx.x >> 1) * 64, d0 = (blockIdx.x & 1) * 64;
  const int t0 = b * S_;
  __shared__ u16 tile[64][72];
  const int tid = threadIdx.x;
#pragma unroll
  for (int i = 0; i < 2; ++i) {
    int c = tid + i * 256;
    int row = c >> 3, off = (c & 7) * 8;
    *(uint4*)&tile[row][off] =
        *(const uint4*)(KVbf + (size_t)(t0 + s0 + row) * 4096 + h * 256 + 128 + d0 + off);
  }
  __syncthreads();
#pragma unroll
  for (int i = 0; i < 2; ++i) {
    int c = tid + i * 256;
    int drow = c >> 3, soff = (c & 7) * 8;
    u16 vals[8];
#pragma unroll
    for (int j = 0; j < 8; ++j) vals[j] = tile[soff + j][drow];
    *(uint4*)(Vt + ((size_t)(b * NH_ + h) * 128 + d0 + drow) * 2048 + s0 + soff) =
        *(uint4*)vals;
  }
}

// ---------------------------------------------------------------------------
// MFMA flash attention v8: v4's 8-wave math (fastest measured, 146 us) with
// SINGLE-buffered K/V (40 KB LDS) -> 4 blocks/CU = 32 waves/CU (VGPR 56 <= 64,
// launch_bounds(512,8)). Trades in-block prefetch for 2x block-level TLP:
// during one block's staging drain / serial softmax, 3 other blocks issue
// MFMA (m114: co-resident waves overlap fully). 2-barrier pattern is the
// proven gemm_mfma structure. Math per element IDENTICAL to v4/v7 (scheduling
// cannot change IEEE-deterministic op results); alpha-skip (bit-exact) and
// setprio retained — both correctness-proven in rounds 6/8/9.
// ---------------------------------------------------------------------------
__global__ __launch_bounds__(512, 8) void flash_mfma(
    const u16* __restrict__ Qbf,
    const u16* __restrict__ KVbf,
    const u16* __restrict__ KPE,
    const u16* __restrict__ Vt,
    u16* __restrict__ Out) {
  const int h = blockIdx.y, b = blockIdx.z;
  const int q0 = blockIdx.x * 128;
  const int t0 = b * S_;
  const int tid = threadIdx.x;
  const int wave = tid >> 6, lane = tid & 63, quad = lane >> 4, l16 = lane & 15;

  __shared__ u16 Ks[64 * 192];   // 24 KB, granule [kk(4)][cc(24)][r16]
  __shared__ u16 Vs[128 * 64];   // 16 KB, granule [dt(8)][kc(8)][r16]

  // Q fragments: wave owns q-rows q0 + wave*16 + [0,16); lane.l16 = q-row.
  bf16x8 qf[6];
  {
    const u16* qp = Qbf + (size_t)(t0 + q0 + wave * 16 + l16) * (NH_ * DQK) + h * DQK + quad * 8;
#pragma unroll
    for (int c = 0; c < 6; ++c) qf[c] = *(const bf16x8*)(qp + c * 32);
  }

  // staging source pointers (granule g = i*512 + tid)
  const u16* kbase[3]; int kstep[3];
#pragma unroll
  for (int i = 0; i < 3; ++i) {
    int g = i * 512 + tid;
    int r = g & 15, cc = (g >> 4) % 24, kk = (g >> 4) / 24;
    int tok = kk * 16 + r;
    if (cc < 16) { kbase[i] = KVbf + (size_t)(t0 + tok) * 4096 + h * 256 + cc * 8; kstep[i] = 64 * 4096; }
    else         { kbase[i] = KPE + (size_t)(t0 + tok) * 64 + (cc - 16) * 8;       kstep[i] = 64 * 64; }
  }
  const u16* vbase[2];
#pragma unroll
  for (int i = 0; i < 2; ++i) {
    int g = i * 512 + tid;
    int r = g & 15, kc = (g >> 4) & 7, dt = g >> 7;
    vbase[i] = Vt + ((size_t)((b * NH_ + h) * 128) + dt * 16 + r) * 2048 + kc * 8;
  }

  f32x4 of[8];
#pragma unroll
  for (int i = 0; i < 8; ++i) of[i] = (f32x4){0.f, 0.f, 0.f, 0.f};
  float mrun = -3e38f, lrun = 0.f;

  // shuffle geometry for building the PV P-fragment:
  //   target key = c2*32 + quad*8 + j  ->  reg pb[c2*2 + (quad>>1)],
  //   src lane = ((quad&1)*2 + (j>>2))*16 + l16
  const int src_lo = (quad & 1) * 32 + l16;
  const int src_hi = src_lo + 16;
  const bool hi_kk = (quad >> 1) != 0;

  for (int it = 0; it < S_ / 64; ++it) {
    __syncthreads();   // all waves done reading the buffer (trivial at it=0)
#pragma unroll
    for (int i = 0; i < 3; ++i) { GLD16(kbase[i], &Ks[(i * 512 + tid) * 8]); kbase[i] += kstep[i]; }
#pragma unroll
    for (int i = 0; i < 2; ++i) GLD16(vbase[i] + it * 64, &Vs[(i * 512 + tid) * 8]);
    __syncthreads();   // vmcnt(0) drain: tile staged + visible

    // ---- scores, SWAPPED: sc[kk] at lane(quad,l16) = S[key=kk*16+quad*4+r][q=l16]
    __builtin_amdgcn_s_setprio(1);
    f32x4 sc[4];
#pragma unroll
    for (int kk = 0; kk < 4; ++kk) {
      f32x4 s = (f32x4){0.f, 0.f, 0.f, 0.f};
#pragma unroll
      for (int c = 0; c < 6; ++c) {
        bf16x8 kf = *(const bf16x8*)&Ks[((kk * 24 + c * 4 + quad) * 16 + l16) * 8];
        s = __builtin_amdgcn_mfma_f32_16x16x32_bf16(kf, qf[c], s, 0, 0, 0);
      }
      sc[kk] = s;
    }
    __builtin_amdgcn_s_setprio(0);

    // ---- online softmax: all 16 values in-lane belong to q = l16 ----
    float tm = sc[0][0];
#pragma unroll
    for (int kk = 0; kk < 4; ++kk)
#pragma unroll
      for (int r = 0; r < 4; ++r) tm = fmaxf(tm, sc[kk][r]);
    tm = fmaxf(tm, __shfl_xor(tm, 16, 64));   // reduce across the 4 quads
    tm = fmaxf(tm, __shfl_xor(tm, 32, 64));
    const bool up = __any(tm > mrun);  // wave-uniform; alpha==1 exactly when false
    float alpha = 1.f;
    if (up) {
      float mnew = fmaxf(mrun, tm);
      alpha = __expf(mrun - mnew);
      mrun = mnew;
    }
    float lsum = 0.f;
#pragma unroll
    for (int kk = 0; kk < 4; ++kk)
#pragma unroll
      for (int r = 0; r < 4; ++r) {
        float p = __expf(sc[kk][r] - mrun);
        sc[kk][r] = p;        // reuse as P
        lsum += p;
      }
    lsum += __shfl_xor(lsum, 16, 64);
    lsum += __shfl_xor(lsum, 32, 64);
    lrun = lrun * alpha + lsum;

    // ---- pack P to bf16 pairs (keys kk*16+quad*4+{0..3}, q=l16) ----
    unsigned pb[4][2];
#pragma unroll
    for (int kk = 0; kk < 4; ++kk) {
      pb[kk][0] = (unsigned)f2b(sc[kk][0]) | ((unsigned)f2b(sc[kk][1]) << 16);
      pb[kk][1] = (unsigned)f2b(sc[kk][2]) | ((unsigned)f2b(sc[kk][3]) << 16);
    }

    // ---- build PV fragments pa[c2]: lane needs P[q=l16][k=c2*32+quad*8+j] ----
    bf16x8 pa[2];
#pragma unroll
    for (int c2 = 0; c2 < 2; ++c2) {
      unsigned a0 = __shfl(pb[c2 * 2][0], src_lo, 64);
      unsigned b0 = __shfl(pb[c2 * 2 + 1][0], src_lo, 64);
      unsigned a1 = __shfl(pb[c2 * 2][1], src_lo, 64);
      unsigned b1 = __shfl(pb[c2 * 2 + 1][1], src_lo, 64);
      unsigned a2 = __shfl(pb[c2 * 2][0], src_hi, 64);
      unsigned b2 = __shfl(pb[c2 * 2 + 1][0], src_hi, 64);
      unsigned a3 = __shfl(pb[c2 * 2][1], src_hi, 64);
      unsigned b3 = __shfl(pb[c2 * 2 + 1][1], src_hi, 64);
      union { unsigned w[4]; bf16x8 v; } u;
      u.w[0] = hi_kk ? b0 : a0;
      u.w[1] = hi_kk ? b1 : a1;
      u.w[2] = hi_kk ? b2 : a2;
      u.w[3] = hi_kk ? b3 : a3;
      pa[c2] = u.v;
    }

    // ---- O rescale only when the running max actually moved (bit-exact skip)
    if (up) {
#pragma unroll
      for (int dt = 0; dt < 8; ++dt)
#pragma unroll
        for (int r = 0; r < 4; ++r) of[dt][r] *= alpha;
    }

    // ---- PV: of[dt] = O[q=l16][d=dt*16+quad*4+r] ----
    __builtin_amdgcn_s_setprio(1);
#pragma unroll
    for (int dt = 0; dt < 8; ++dt) {
#pragma unroll
      for (int c2 = 0; c2 < 2; ++c2) {
        bf16x8 vf = *(const bf16x8*)&Vs[((dt * 8 + c2 * 4 + quad) * 16 + l16) * 8];
        of[dt] = __builtin_amdgcn_mfma_f32_16x16x32_bf16(vf, pa[c2], of[dt], 0, 0, 0);
      }
    }
    __builtin_amdgcn_s_setprio(0);
  }

  // epilogue: lane holds O[q=l16][d=dt*16+quad*4+{0..3}] -> uint2 stores
  float inv = 1.0f / lrun;
  u16* op = Out + (size_t)(t0 + q0 + wave * 16 + l16) * (NH_ * DV) + h * DV + quad * 4;
#pragma unroll
  for (int dt = 0; dt < 8; ++dt) {
    u16 r4[4] = {f2b(of[dt][0] * inv), f2b(of[dt][1] * inv),
                 f2b(of[dt][2] * inv), f2b(of[dt][3] * inv)};
    *(uint2*)(op + dt * 16) = *(uint2*)r4;
  }
}

// ---------------------------------------------------------------------------
// Workspace (float units), total 38,273,024 fl = 153.1 MB.
// qn_bf (3,145,728 fl) aliases the kv_bf region [29884416,33030144):
// written step 3 (kv_bf dead), read step 4, clobbered step 8 (qn_bf dead).
// attn_bf [11927552,16121856) + vt [16121856,20316160) inside dead qkv_a.
// rope_tab [20840448,20971520) in the spare region: written dispatch 2,
// read by rope_q (disp 5) and kpe (disp 7); overlaps nothing.
// Full region map (fl):
//   hid_bf   [0,        4194304)   wqa_bf  [4194304,  5767168)
//   wkva_bf  [5767168,  6422528)   wqb_bf  [6422528,  8781824)
//   wkvb_bf  [8781824,  9830400)   wo_bf   [9830400, 11927552)
//   qkv_a    [11927552, 20840448)  (attn_bf/vt alias inside)
//   rope_tab [20840448, 20971520)  (spare cont. to 22413312)
//   q_bf     [22413312, 28704768)  kvn_bf  [28704768, 29753344)
//   kpe      [29753344, 29884416)  kv_bf   [29884416, 38273024)
//   qn_bf    = alias of kv_bf[0:3145728)
// ---------------------------------------------------------------------------
extern "C" void kernel_launch(void* const* d_in, const int* in_sizes, int n_in,
                              void* d_out, int out_size, void* d_ws, size_t ws_size,
                              hipStream_t stream) {
  const float* hidden  = (const float*)d_in[0];
  const float* wq_a    = (const float*)d_in[1];
  const float* q_norm  = (const float*)d_in[2];
  const float* wq_b    = (const float*)d_in[3];
  const float* wkv_a   = (const float*)d_in[4];
  const float* kv_norm = (const float*)d_in[5];
  const float* wkv_b   = (const float*)d_in[6];
  const float* wo      = (const float*)d_in[7];
  float* out = (float*)d_out;

  float* ws = (float*)d_ws;
  u16*   hid_bf  = (u16*)(ws);                  // 8,388,608 u16 -> 4,194,304 fl
  u16*   wqa_bf  = (u16*)(ws + 4194304);        // 3,145,728 u16 -> 1,572,864 fl
  u16*   wkva_bf = (u16*)(ws + 5767168);        // 1,310,720 u16 ->   655,360 fl (adjacent to wqa)
  u16*   wqb_bf  = (u16*)(ws + 6422528);        // 4,718,592 u16 -> 2,359,296 fl
  u16*   wkvb_bf = (u16*)(ws + 8781824);        // 2,097,152 u16 -> 1,048,576 fl
  u16*   wo_bf   = (u16*)(ws + 9830400);        // 4,194,304 u16 -> 2,097,152 fl
  float* qkv_a   = ws + 11927552;               // 8,912,896 fl (4096 x 2176)
  u16*   attn_bf = (u16*)(ws + 11927552);       //   alias: 8,388,608 u16 (4,194,304 fl)
  u16*   vt      = (u16*)(ws + 16121856);       //   alias: 8,388,608 u16 (4,194,304 fl)
  float* rope_tab = ws + 20840448;              //   131,072 fl (65536 float2)
  u16*   q_bf    = (u16*)(ws + 22413312);       // 12,582,912 u16 -> 6,291,456 fl
  u16*   kvn_bf  = (u16*)(ws + 28704768);       // 2,097,152 u16 -> 1,048,576 fl
  u16*   kpe     = (u16*)(ws + 29753344);       //   262,144 u16 ->   131,072 fl
  u16*   kv_bf   = (u16*)(ws + 29884416);       // 16,777,216 u16 -> 8,388,608 fl
  u16*   qn_bf   = (u16*)(ws + 29884416);       //   alias of kv_bf: 6,291,456 u16 -> 3,145,728 fl
  const size_t need = (size_t)38273024 * sizeof(float);
  if (ws_size < need) return;

  // one fused conversion pass: hidden + all weights
  cvt_all<<<23296, 256, 0, stream>>>(hidden, wq_a, wq_b, wkv_a, wkv_b, wo,
                                     hid_bf, wqa_bf, wqb_bf, wkva_bf, wkvb_bf, wo_bf);

  // rope cos/sin table (bit-identical values, computed once)
  rope_tab_kernel<<<S_ * 32 / 256, 256, 0, stream>>>(rope_tab);

  // ---- fused q_a + kv_a GEMM: [4096x2048] @ [2176x2048]^T -> qkv_a ----
  gemm_mfma<0><<<dim3(NQKV / 128, T_ / 128), 256, 0, stream>>>(
      hid_bf, H_, wqa_bf, H_, qkv_a, nullptr, NQKV, H_, 1.0f);

  // ---- q path ----
  rmsnorm_bf<<<T_, 256, 0, stream>>>(qkv_a, q_norm, qn_bf, QL, NQKV, QL);
  gemm_mfma<1><<<dim3(NH_ * DQK / 128, T_ / 128), 256, 0, stream>>>(
      qn_bf, QL, wqb_bf, QL, nullptr, q_bf, NH_ * DQK, QL, SCALE_);
  rope_q_bf<<<T_ * NH_ * 32 / 256, 256, 0, stream>>>(q_bf, rope_tab);

  // ---- kv path ----
  rmsnorm_bf<<<T_, 256, 0, stream>>>(qkv_a + QL, kv_norm, kvn_bf, KVL, NQKV, KVL);
  kpe_bf_kernel<<<T_ * 32 / 256, 256, 0, stream>>>(qkv_a, kpe, rope_tab);
  gemm_mfma<1><<<dim3(NH_ * (DN + DV) / 128, T_ / 128), 256, 0, stream>>>(
      kvn_bf, KVL, wkvb_bf, KVL, nullptr, kv_bf, NH_ * (DN + DV), KVL, 1.0f);
  conv_vt<<<dim3(64, NH_, B_), 256, 0, stream>>>(kv_bf, vt);

  // ---- attention ----
  flash_mfma<<<dim3(S_ / 128, NH_, B_), 512, 0, stream>>>(q_bf, kv_bf, kpe, vt, attn_bf);

  // ---- out = attn @ wo.T ----
  gemm_mfma<0><<<dim3(H_ / 128, T_ / 128), 256, 0, stream>>>(
      attn_bf, NH_ * DV, wo_bf, NH_ * DV, out, nullptr, H_, NH_ * DV, 1.0f);
}

// Round 11
// 572.354 us; speedup vs baseline: 1.6118x; 1.6118x over previous
//
#include <hip/hip_runtime.h>
#include <math.h>

#define B_   2
#define S_   2048
#define H_   2048
#define NH_  16
#define T_   (B_*S_)      // 4096 tokens
#define QL   1536
#define KVL  512
#define DN   128
#define DR   64
#define DQK  192          // DN + DR
#define DV   128
#define SCALE_ 0.07216878364870323f   // 1/sqrt(192)
#define EPS_ 1e-6f
#define NQKV 2176                     // fused q_a(1536) + kv_a(640) output cols

typedef unsigned short u16;
typedef __attribute__((ext_vector_type(8))) short bf16x8;  // 8 bf16 = 4 VGPRs
typedef __attribute__((ext_vector_type(4))) float f32x4;   // MFMA C/D frag

__device__ __forceinline__ u16 f2b(float x) {   // fp32 -> bf16 RNE
  union { float f; unsigned u; } v; v.f = x;
  unsigned r = v.u + 0x7FFFu + ((v.u >> 16) & 1u);
  return (u16)(r >> 16);
}
__device__ __forceinline__ float b2f(u16 u) {
  union { unsigned u; float f; } v; v.u = ((unsigned)u) << 16; return v.f;
}

#define GLD16(src, dst) __builtin_amdgcn_global_load_lds(                       \
    (const __attribute__((address_space(1))) unsigned int*)(src),               \
    (__attribute__((address_space(3))) unsigned int*)(dst), 16, 0, 0)

__device__ __forceinline__ void cvt4(const float* in, u16* out, int i) {
  float4 v = ((const float4*)in)[i];
  u16 r[4] = {f2b(v.x), f2b(v.y), f2b(v.z), f2b(v.w)};
  ((uint2*)out)[i] = *(uint2*)r;
}

// ---------------------------------------------------------------------------
// One fused conversion kernel: hidden + all 4 weights (wkv_a padded 576->640).
// ---------------------------------------------------------------------------
__global__ __launch_bounds__(256) void cvt_all(
    const float* __restrict__ hid, const float* __restrict__ wqa,
    const float* __restrict__ wqb, const float* __restrict__ wkva,
    const float* __restrict__ wkvb, const float* __restrict__ wo,
    u16* __restrict__ o_hid, u16* __restrict__ o_wqa, u16* __restrict__ o_wqb,
    u16* __restrict__ o_wkva, u16* __restrict__ o_wkvb, u16* __restrict__ o_wo) {
  int i = blockIdx.x * 256 + threadIdx.x;
  if (i < 2097152) { cvt4(hid, o_hid, i); return; }
  i -= 2097152;
  if (i < 786432) { cvt4(wqa, o_wqa, i); return; }
  i -= 786432;
  if (i < 1179648) { cvt4(wqb, o_wqb, i); return; }
  i -= 1179648;
  if (i < 327680) {                       // wkv_a with zero-pad rows [576,640)
    int row = i >> 9;
    u16 r[4] = {0, 0, 0, 0};
    if (row < 576) {
      float4 v = ((const float4*)wkva)[i];
      r[0] = f2b(v.x); r[1] = f2b(v.y); r[2] = f2b(v.z); r[3] = f2b(v.w);
    }
    ((uint2*)o_wkva)[i] = *(uint2*)r;
    return;
  }
  i -= 327680;
  if (i < 524288) { cvt4(wkvb, o_wkvb, i); return; }
  i -= 524288;
  if (i < 1048576) cvt4(wo, o_wo, i);
}

// ---------------------------------------------------------------------------
// bf16 MFMA GEMM: C = A @ W^T — round-5/6 measured-best BK=32 version.
// ---------------------------------------------------------------------------
template <int OUTMODE>
__global__ __launch_bounds__(256) void gemm_mfma(
    const u16* __restrict__ A, int lda,
    const u16* __restrict__ W, int ldw,
    float* __restrict__ Cf, u16* __restrict__ Cb, int ldc,
    int K, float outscale) {
  __shared__ u16 As[4096];   // 8 KB
  __shared__ u16 Bs[4096];
  const int tid = threadIdx.x;
  const int wave = tid >> 6, lane = tid & 63, quad = lane >> 4, l16 = lane & 15;
  const int wm = (wave >> 1) * 64, wn = (wave & 1) * 64;
  const size_t m0 = (size_t)blockIdx.y * 128, n0 = (size_t)blockIdx.x * 128;

  f32x4 acc[4][4];
#pragma unroll
  for (int i = 0; i < 4; ++i)
#pragma unroll
    for (int j = 0; j < 4; ++j) acc[i][j] = (f32x4){0.f, 0.f, 0.f, 0.f};

  const int g0 = tid, g1 = tid + 256;
  const u16* a0 = A + (m0 + (g0 >> 6) * 16 + (g0 & 15)) * (size_t)lda + ((g0 >> 4) & 3) * 8;
  const u16* a1 = A + (m0 + (g1 >> 6) * 16 + (g1 & 15)) * (size_t)lda + ((g1 >> 4) & 3) * 8;
  const u16* b0 = W + (n0 + (g0 >> 6) * 16 + (g0 & 15)) * (size_t)ldw + ((g0 >> 4) & 3) * 8;
  const u16* b1 = W + (n0 + (g1 >> 6) * 16 + (g1 & 15)) * (size_t)ldw + ((g1 >> 4) & 3) * 8;

  for (int k0 = 0; k0 < K; k0 += 32) {
    __syncthreads();
    GLD16(a0 + k0, &As[g0 * 8]);
    GLD16(a1 + k0, &As[g1 * 8]);
    GLD16(b0 + k0, &Bs[g0 * 8]);
    GLD16(b1 + k0, &Bs[g1 * 8]);
    __syncthreads();

    bf16x8 af[4], bfr[4];
#pragma unroll
    for (int i = 0; i < 4; ++i)
      af[i] = *(const bf16x8*)&As[((wm >> 4) + i) * 512 + quad * 128 + l16 * 8];
#pragma unroll
    for (int j = 0; j < 4; ++j)
      bfr[j] = *(const bf16x8*)&Bs[((wn >> 4) + j) * 512 + quad * 128 + l16 * 8];
#pragma unroll
    for (int i = 0; i < 4; ++i)
#pragma unroll
      for (int j = 0; j < 4; ++j)
        acc[i][j] = __builtin_amdgcn_mfma_f32_16x16x32_bf16(af[i], bfr[j], acc[i][j], 0, 0, 0);
  }

#pragma unroll
  for (int i = 0; i < 4; ++i)
#pragma unroll
    for (int j = 0; j < 4; ++j)
#pragma unroll
      for (int r = 0; r < 4; ++r) {
        size_t m = m0 + wm + i * 16 + quad * 4 + r;
        size_t n = n0 + wn + j * 16 + l16;
        if (OUTMODE == 0) Cf[m * ldc + n] = acc[i][j][r];
        else              Cb[m * ldc + n] = f2b(acc[i][j][r] * outscale);
      }
}

// ---------------------------------------------------------------------------
// RMSNorm: fp32 in (row stride sx), bf16 out (row stride so), D cols.
// ---------------------------------------------------------------------------
__global__ __launch_bounds__(256) void rmsnorm_bf(
    const float* __restrict__ x, const float* __restrict__ w,
    u16* __restrict__ o, int D, int sx, int so) {
  const float* p = x + (size_t)blockIdx.x * sx;
  u16* q = o + (size_t)blockIdx.x * so;
  float ss = 0.f;
  for (int i = threadIdx.x; i < D; i += 256) { float v = p[i]; ss += v * v; }
#pragma unroll
  for (int off = 32; off; off >>= 1) ss += __shfl_down(ss, off);
  __shared__ float red[4];
  __shared__ float s_inv;
  if ((threadIdx.x & 63) == 0) red[threadIdx.x >> 6] = ss;
  __syncthreads();
  if (threadIdx.x == 0) {
    float t = red[0] + red[1] + red[2] + red[3];
    s_inv = 1.0f / sqrtf(t / (float)D + EPS_);
  }
  __syncthreads();
  float inv = s_inv;
  for (int i = threadIdx.x; i < D; i += 256) q[i] = f2b(w[i] * p[i] * inv);
}

// ---------------------------------------------------------------------------
// RoPE cos/sin table: bit-identical expressions, computed once (65536 entries).
// ---------------------------------------------------------------------------
__global__ __launch_bounds__(256) void rope_tab_kernel(float* __restrict__ Tab) {
  int idx = blockIdx.x * 256 + threadIdx.x;   // S_*32 = 65536
  int pair = idx & 31;
  int s = idx >> 5;
  float inv = powf(10000.0f, -(float)(2 * pair) * (1.0f / 64.0f));
  float ang = (float)s * inv;
  ((float2*)Tab)[idx] = make_float2(cosf(ang), sinf(ang));
}

// RoPE in place on bf16 q_pe. Q: [T][NH*192], pe at +128 per head.
__global__ void rope_q_bf(u16* __restrict__ Q, const float* __restrict__ Tab) {
  int idx = blockIdx.x * blockDim.x + threadIdx.x;   // T*NH*32
  int pair = idx & 31;
  int head = (idx >> 5) & (NH_ - 1);
  int row = idx >> 9;
  if (row >= T_) return;
  int s = row & (S_ - 1);
  float2 cs = ((const float2*)Tab)[(s << 5) | pair];
  float c = cs.x, sn = cs.y;
  u16* p = Q + (size_t)row * (NH_ * DQK) + head * DQK + DN + 2 * pair;
  unsigned u = *(unsigned*)p;
  float e = b2f((u16)(u & 0xffff)), o = b2f((u16)(u >> 16));
  float re = e * c - o * sn;
  float im = e * sn + o * c;
  *(unsigned*)p = (unsigned)f2b(re) | ((unsigned)f2b(im) << 16);
}

// k_pe: fp32 qkv_a cols [2048,2112) (row stride 2176), rope -> bf16 KPE [T][64].
__global__ void kpe_bf_kernel(const float* __restrict__ KVa, u16* __restrict__ KPE,
                              const float* __restrict__ Tab) {
  int idx = blockIdx.x * blockDim.x + threadIdx.x;   // T*32
  int pair = idx & 31;
  int row = idx >> 5;
  if (row >= T_) return;
  int s = row & (S_ - 1);
  float2 cs = ((const float2*)Tab)[(s << 5) | pair];
  float c = cs.x, sn = cs.y;
  const float* p = KVa + (size_t)row * NQKV + 2048 + 2 * pair;
  float e = p[0], o = p[1];
  float re = e * c - o * sn;
  float im = e * sn + o * c;
  *(unsigned*)(KPE + (size_t)row * 64 + 2 * pair) =
      (unsigned)f2b(re) | ((unsigned)f2b(im) << 16);
}

// ---------------------------------------------------------------------------
// V transpose: KVbf [T][NH*256] (v at +128 per head) -> Vt [B*NH*128][2048].
// ---------------------------------------------------------------------------
__global__ __launch_bounds__(256) void conv_vt(const u16* __restrict__ KVbf,
                                               u16* __restrict__ Vt) {
  const int h = blockIdx.y, b = blockIdx.z;
  const int s0 = (blockIdx.x >> 1) * 64, d0 = (blockIdx.x & 1) * 64;
  const int t0 = b * S_;
  __shared__ u16 tile[64][72];
  const int tid = threadIdx.x;
#pragma unroll
  for (int i = 0; i < 2; ++i) {
    int c = tid + i * 256;
    int row = c >> 3, off = (c & 7) * 8;
    *(uint4*)&tile[row][off] =
        *(const uint4*)(KVbf + (size_t)(t0 + s0 + row) * 4096 + h * 256 + 128 + d0 + off);
  }
  __syncthreads();
#pragma unroll
  for (int i = 0; i < 2; ++i) {
    int c = tid + i * 256;
    int drow = c >> 3, soff = (c & 7) * 8;
    u16 vals[8];
#pragma unroll
    for (int j = 0; j < 8; ++j) vals[j] = tile[soff + j][drow];
    *(uint4*)(Vt + ((size_t)(b * NH_ + h) * 128 + d0 + drow) * 2048 + s0 + soff) =
        *(uint4*)vals;
  }
}

// ---------------------------------------------------------------------------
// MFMA flash attention v8b: single-buffered K/V (40 KB LDS -> 4 blocks/CU)
// with launch_bounds(512, 4). [Round-10 post-mortem: (512,8) capped the
// allocator at 32 VGPRs -> everything spilled to scratch (FETCH 145K->1.1M KB,
// flash 488 us). The TLP experiment never ran. (512,4) gives a 128-VGPR
// budget; the identical math compiled to 56 VGPRs at this bound in rounds
// 1-5, so no spill, and LDS still admits 4 blocks/CU = up to 32 waves.]
// Theory unchanged: during one block's staging drain / serial softmax, 3
// other blocks issue MFMA (m114). Math per element identical to v4.
// Pre-committed decision rule: if flash >= 146 us, single-buffer is
// falsified -> revert to v4-dbuf next round.
// ---------------------------------------------------------------------------
__global__ __launch_bounds__(512, 4) void flash_mfma(
    const u16* __restrict__ Qbf,
    const u16* __restrict__ KVbf,
    const u16* __restrict__ KPE,
    const u16* __restrict__ Vt,
    u16* __restrict__ Out) {
  const int h = blockIdx.y, b = blockIdx.z;
  const int q0 = blockIdx.x * 128;
  const int t0 = b * S_;
  const int tid = threadIdx.x;
  const int wave = tid >> 6, lane = tid & 63, quad = lane >> 4, l16 = lane & 15;

  __shared__ u16 Ks[64 * 192];   // 24 KB, granule [kk(4)][cc(24)][r16]
  __shared__ u16 Vs[128 * 64];   // 16 KB, granule [dt(8)][kc(8)][r16]

  // Q fragments: wave owns q-rows q0 + wave*16 + [0,16); lane.l16 = q-row.
  bf16x8 qf[6];
  {
    const u16* qp = Qbf + (size_t)(t0 + q0 + wave * 16 + l16) * (NH_ * DQK) + h * DQK + quad * 8;
#pragma unroll
    for (int c = 0; c < 6; ++c) qf[c] = *(const bf16x8*)(qp + c * 32);
  }

  // staging source pointers (granule g = i*512 + tid)
  const u16* kbase[3]; int kstep[3];
#pragma unroll
  for (int i = 0; i < 3; ++i) {
    int g = i * 512 + tid;
    int r = g & 15, cc = (g >> 4) % 24, kk = (g >> 4) / 24;
    int tok = kk * 16 + r;
    if (cc < 16) { kbase[i] = KVbf + (size_t)(t0 + tok) * 4096 + h * 256 + cc * 8; kstep[i] = 64 * 4096; }
    else         { kbase[i] = KPE + (size_t)(t0 + tok) * 64 + (cc - 16) * 8;       kstep[i] = 64 * 64; }
  }
  const u16* vbase[2];
#pragma unroll
  for (int i = 0; i < 2; ++i) {
    int g = i * 512 + tid;
    int r = g & 15, kc = (g >> 4) & 7, dt = g >> 7;
    vbase[i] = Vt + ((size_t)((b * NH_ + h) * 128) + dt * 16 + r) * 2048 + kc * 8;
  }

  f32x4 of[8];
#pragma unroll
  for (int i = 0; i < 8; ++i) of[i] = (f32x4){0.f, 0.f, 0.f, 0.f};
  float mrun = -3e38f, lrun = 0.f;

  // shuffle geometry for building the PV P-fragment:
  //   target key = c2*32 + quad*8 + j  ->  reg pb[c2*2 + (quad>>1)],
  //   src lane = ((quad&1)*2 + (j>>2))*16 + l16
  const int src_lo = (quad & 1) * 32 + l16;
  const int src_hi = src_lo + 16;
  const bool hi_kk = (quad >> 1) != 0;

  for (int it = 0; it < S_ / 64; ++it) {
    __syncthreads();   // all waves done reading the buffer (trivial at it=0)
#pragma unroll
    for (int i = 0; i < 3; ++i) { GLD16(kbase[i], &Ks[(i * 512 + tid) * 8]); kbase[i] += kstep[i]; }
#pragma unroll
    for (int i = 0; i < 2; ++i) GLD16(vbase[i] + it * 64, &Vs[(i * 512 + tid) * 8]);
    __syncthreads();   // vmcnt(0) drain: tile staged + visible

    // ---- scores, SWAPPED: sc[kk] at lane(quad,l16) = S[key=kk*16+quad*4+r][q=l16]
    __builtin_amdgcn_s_setprio(1);
    f32x4 sc[4];
#pragma unroll
    for (int kk = 0; kk < 4; ++kk) {
      f32x4 s = (f32x4){0.f, 0.f, 0.f, 0.f};
#pragma unroll
      for (int c = 0; c < 6; ++c) {
        bf16x8 kf = *(const bf16x8*)&Ks[((kk * 24 + c * 4 + quad) * 16 + l16) * 8];
        s = __builtin_amdgcn_mfma_f32_16x16x32_bf16(kf, qf[c], s, 0, 0, 0);
      }
      sc[kk] = s;
    }
    __builtin_amdgcn_s_setprio(0);

    // ---- online softmax: all 16 values in-lane belong to q = l16 ----
    float tm = sc[0][0];
#pragma unroll
    for (int kk = 0; kk < 4; ++kk)
#pragma unroll
      for (int r = 0; r < 4; ++r) tm = fmaxf(tm, sc[kk][r]);
    tm = fmaxf(tm, __shfl_xor(tm, 16, 64));   // reduce across the 4 quads
    tm = fmaxf(tm, __shfl_xor(tm, 32, 64));
    const bool up = __any(tm > mrun);  // wave-uniform; alpha==1 exactly when false
    float alpha = 1.f;
    if (up) {
      float mnew = fmaxf(mrun, tm);
      alpha = __expf(mrun - mnew);
      mrun = mnew;
    }
    float lsum = 0.f;
#pragma unroll
    for (int kk = 0; kk < 4; ++kk)
#pragma unroll
      for (int r = 0; r < 4; ++r) {
        float p = __expf(sc[kk][r] - mrun);
        sc[kk][r] = p;        // reuse as P
        lsum += p;
      }
    lsum += __shfl_xor(lsum, 16, 64);
    lsum += __shfl_xor(lsum, 32, 64);
    lrun = lrun * alpha + lsum;

    // ---- pack P to bf16 pairs (keys kk*16+quad*4+{0..3}, q=l16) ----
    unsigned pb[4][2];
#pragma unroll
    for (int kk = 0; kk < 4; ++kk) {
      pb[kk][0] = (unsigned)f2b(sc[kk][0]) | ((unsigned)f2b(sc[kk][1]) << 16);
      pb[kk][1] = (unsigned)f2b(sc[kk][2]) | ((unsigned)f2b(sc[kk][3]) << 16);
    }

    // ---- build PV fragments pa[c2]: lane needs P[q=l16][k=c2*32+quad*8+j] ----
    bf16x8 pa[2];
#pragma unroll
    for (int c2 = 0; c2 < 2; ++c2) {
      unsigned a0 = __shfl(pb[c2 * 2][0], src_lo, 64);
      unsigned b0 = __shfl(pb[c2 * 2 + 1][0], src_lo, 64);
      unsigned a1 = __shfl(pb[c2 * 2][1], src_lo, 64);
      unsigned b1 = __shfl(pb[c2 * 2 + 1][1], src_lo, 64);
      unsigned a2 = __shfl(pb[c2 * 2][0], src_hi, 64);
      unsigned b2 = __shfl(pb[c2 * 2 + 1][0], src_hi, 64);
      unsigned a3 = __shfl(pb[c2 * 2][1], src_hi, 64);
      unsigned b3 = __shfl(pb[c2 * 2 + 1][1], src_hi, 64);
      union { unsigned w[4]; bf16x8 v; } u;
      u.w[0] = hi_kk ? b0 : a0;
      u.w[1] = hi_kk ? b1 : a1;
      u.w[2] = hi_kk ? b2 : a2;
      u.w[3] = hi_kk ? b3 : a3;
      pa[c2] = u.v;
    }

    // ---- O rescale only when the running max actually moved (bit-exact skip)
    if (up) {
#pragma unroll
      for (int dt = 0; dt < 8; ++dt)
#pragma unroll
        for (int r = 0; r < 4; ++r) of[dt][r] *= alpha;
    }

    // ---- PV: of[dt] = O[q=l16][d=dt*16+quad*4+r] ----
    __builtin_amdgcn_s_setprio(1);
#pragma unroll
    for (int dt = 0; dt < 8; ++dt) {
#pragma unroll
      for (int c2 = 0; c2 < 2; ++c2) {
        bf16x8 vf = *(const bf16x8*)&Vs[((dt * 8 + c2 * 4 + quad) * 16 + l16) * 8];
        of[dt] = __builtin_amdgcn_mfma_f32_16x16x32_bf16(vf, pa[c2], of[dt], 0, 0, 0);
      }
    }
    __builtin_amdgcn_s_setprio(0);
  }

  // epilogue: lane holds O[q=l16][d=dt*16+quad*4+{0..3}] -> uint2 stores
  float inv = 1.0f / lrun;
  u16* op = Out + (size_t)(t0 + q0 + wave * 16 + l16) * (NH_ * DV) + h * DV + quad * 4;
#pragma unroll
  for (int dt = 0; dt < 8; ++dt) {
    u16 r4[4] = {f2b(of[dt][0] * inv), f2b(of[dt][1] * inv),
                 f2b(of[dt][2] * inv), f2b(of[dt][3] * inv)};
    *(uint2*)(op + dt * 16) = *(uint2*)r4;
  }
}

// ---------------------------------------------------------------------------
// Workspace (float units), total 38,273,024 fl = 153.1 MB.
// qn_bf (3,145,728 fl) aliases the kv_bf region [29884416,33030144):
// written step 3 (kv_bf dead), read step 4, clobbered step 8 (qn_bf dead).
// attn_bf [11927552,16121856) + vt [16121856,20316160) inside dead qkv_a.
// rope_tab [20840448,20971520) in the spare region: written dispatch 2,
// read by rope_q (disp 5) and kpe (disp 7); overlaps nothing.
// Full region map (fl):
//   hid_bf   [0,        4194304)   wqa_bf  [4194304,  5767168)
//   wkva_bf  [5767168,  6422528)   wqb_bf  [6422528,  8781824)
//   wkvb_bf  [8781824,  9830400)   wo_bf   [9830400, 11927552)
//   qkv_a    [11927552, 20840448)  (attn_bf/vt alias inside)
//   rope_tab [20840448, 20971520)  (spare cont. to 22413312)
//   q_bf     [22413312, 28704768)  kvn_bf  [28704768, 29753344)
//   kpe      [29753344, 29884416)  kv_bf   [29884416, 38273024)
//   qn_bf    = alias of kv_bf[0:3145728)
// ---------------------------------------------------------------------------
extern "C" void kernel_launch(void* const* d_in, const int* in_sizes, int n_in,
                              void* d_out, int out_size, void* d_ws, size_t ws_size,
                              hipStream_t stream) {
  const float* hidden  = (const float*)d_in[0];
  const float* wq_a    = (const float*)d_in[1];
  const float* q_norm  = (const float*)d_in[2];
  const float* wq_b    = (const float*)d_in[3];
  const float* wkv_a   = (const float*)d_in[4];
  const float* kv_norm = (const float*)d_in[5];
  const float* wkv_b   = (const float*)d_in[6];
  const float* wo      = (const float*)d_in[7];
  float* out = (float*)d_out;

  float* ws = (float*)d_ws;
  u16*   hid_bf  = (u16*)(ws);                  // 8,388,608 u16 -> 4,194,304 fl
  u16*   wqa_bf  = (u16*)(ws + 4194304);        // 3,145,728 u16 -> 1,572,864 fl
  u16*   wkva_bf = (u16*)(ws + 5767168);        // 1,310,720 u16 ->   655,360 fl (adjacent to wqa)
  u16*   wqb_bf  = (u16*)(ws + 6422528);        // 4,718,592 u16 -> 2,359,296 fl
  u16*   wkvb_bf = (u16*)(ws + 8781824);        // 2,097,152 u16 -> 1,048,576 fl
  u16*   wo_bf   = (u16*)(ws + 9830400);        // 4,194,304 u16 -> 2,097,152 fl
  float* qkv_a   = ws + 11927552;               // 8,912,896 fl (4096 x 2176)
  u16*   attn_bf = (u16*)(ws + 11927552);       //   alias: 8,388,608 u16 (4,194,304 fl)
  u16*   vt      = (u16*)(ws + 16121856);       //   alias: 8,388,608 u16 (4,194,304 fl)
  float* rope_tab = ws + 20840448;              //   131,072 fl (65536 float2)
  u16*   q_bf    = (u16*)(ws + 22413312);       // 12,582,912 u16 -> 6,291,456 fl
  u16*   kvn_bf  = (u16*)(ws + 28704768);       // 2,097,152 u16 -> 1,048,576 fl
  u16*   kpe     = (u16*)(ws + 29753344);       //   262,144 u16 ->   131,072 fl
  u16*   kv_bf   = (u16*)(ws + 29884416);       // 16,777,216 u16 -> 8,388,608 fl
  u16*   qn_bf   = (u16*)(ws + 29884416);       //   alias of kv_bf: 6,291,456 u16 -> 3,145,728 fl
  const size_t need = (size_t)38273024 * sizeof(float);
  if (ws_size < need) return;

  // one fused conversion pass: hidden + all weights
  cvt_all<<<23296, 256, 0, stream>>>(hidden, wq_a, wq_b, wkv_a, wkv_b, wo,
                                     hid_bf, wqa_bf, wqb_bf, wkva_bf, wkvb_bf, wo_bf);

  // rope cos/sin table (bit-identical values, computed once)
  rope_tab_kernel<<<S_ * 32 / 256, 256, 0, stream>>>(rope_tab);

  // ---- fused q_a + kv_a GEMM: [4096x2048] @ [2176x2048]^T -> qkv_a ----
  gemm_mfma<0><<<dim3(NQKV / 128, T_ / 128), 256, 0, stream>>>(
      hid_bf, H_, wqa_bf, H_, qkv_a, nullptr, NQKV, H_, 1.0f);

  // ---- q path ----
  rmsnorm_bf<<<T_, 256, 0, stream>>>(qkv_a, q_norm, qn_bf, QL, NQKV, QL);
  gemm_mfma<1><<<dim3(NH_ * DQK / 128, T_ / 128), 256, 0, stream>>>(
      qn_bf, QL, wqb_bf, QL, nullptr, q_bf, NH_ * DQK, QL, SCALE_);
  rope_q_bf<<<T_ * NH_ * 32 / 256, 256, 0, stream>>>(q_bf, rope_tab);

  // ---- kv path ----
  rmsnorm_bf<<<T_, 256, 0, stream>>>(qkv_a + QL, kv_norm, kvn_bf, KVL, NQKV, KVL);
  kpe_bf_kernel<<<T_ * 32 / 256, 256, 0, stream>>>(qkv_a, kpe, rope_tab);
  gemm_mfma<1><<<dim3(NH_ * (DN + DV) / 128, T_ / 128), 256, 0, stream>>>(
      kvn_bf, KVL, wkvb_bf, KVL, nullptr, kv_bf, NH_ * (DN + DV), KVL, 1.0f);
  conv_vt<<<dim3(64, NH_, B_), 256, 0, stream>>>(kv_bf, vt);

  // ---- attention ----
  flash_mfma<<<dim3(S_ / 128, NH_, B_), 512, 0, stream>>>(q_bf, kv_bf, kpe, vt, attn_bf);

  // ---- out = attn @ wo.T ----
  gemm_mfma<0><<<dim3(H_ / 128, T_ / 128), 256, 0, stream>>>(
      attn_bf, NH_ * DV, wo_bf, NH_ * DV, out, nullptr, H_, NH_ * DV, 1.0f);
}